// Round 1
// baseline (921.430 us; speedup 1.0000x reference)
//
#include <hip/hip_runtime.h>
#include <math.h>

#define B_ 16
#define T_ 2048
#define DIM_ 1024
#define MDIM_ 128
#define HID_ 512
#define NCAT 640
#define NW_ 128
#define WINSZ 16
#define MAXP_ 6
#define P_ 768
#define KDROP 614
#define TKEEP 1434
#define NTOK (B_*T_)

// workspace layout (in 4-byte units)
#define OFF_WCAT   0
#define OFF_BIAS   (OFF_WCAT + DIM_*NCAT)
#define OFF_MU     (OFF_BIAS + NCAT)
#define OFF_RS     (OFF_MU + NTOK)
#define OFF_MBUF   (OFF_RS + NTOK)
#define OFF_LOGIT  (OFF_MBUF + NTOK*MDIM_)
#define OFF_IMP    (OFF_LOGIT + NTOK)
#define OFF_IIDX   (OFF_IMP + NTOK)
#define OFF_JIDX   (OFF_IIDX + B_*P_)
#define OFF_SV     (OFF_JIDX + B_*P_)
#define OFF_ALPHA  (OFF_SV + B_*P_)
#define OFF_REP    (OFF_ALPHA + B_*P_)
#define OFF_DROP   (OFF_REP + NTOK)
#define OFF_POS    (OFF_DROP + NTOK)

// ---------------- K0a: Wcat[k][c] = g⊙W concatenated (1024 x 640) ----------------
__global__ __launch_bounds__(256) void build_wcat(const float* __restrict__ wm,
    const float* __restrict__ wi, const float* __restrict__ gm,
    const float* __restrict__ gi, float* __restrict__ Wcat) {
  int e = blockIdx.x * 256 + threadIdx.x;
  if (e >= DIM_ * NCAT) return;
  int k = e / NCAT, c = e - k * NCAT;
  float v = (c < MDIM_) ? gm[k] * wm[k * MDIM_ + c]
                        : gi[k] * wi[k * HID_ + (c - MDIM_)];
  Wcat[e] = v;
}

// ---------------- K0b: biascat[c] = b@W (+ b_imp1 for h part) ----------------
__global__ __launch_bounds__(256) void build_bias(const float* __restrict__ wm,
    const float* __restrict__ wi, const float* __restrict__ bm,
    const float* __restrict__ bi, const float* __restrict__ b1,
    float* __restrict__ biascat) {
  int c = blockIdx.x;
  float s = 0.f;
  for (int k = threadIdx.x; k < DIM_; k += 256)
    s += (c < MDIM_) ? bm[k] * wm[k * MDIM_ + c]
                     : bi[k] * wi[k * HID_ + (c - MDIM_)];
  __shared__ float red[256];
  red[threadIdx.x] = s; __syncthreads();
  for (int o = 128; o > 0; o >>= 1) {
    if (threadIdx.x < o) red[threadIdx.x] += red[threadIdx.x + o];
    __syncthreads();
  }
  if (threadIdx.x == 0)
    biascat[c] = red[0] + ((c >= MDIM_) ? b1[c - MDIM_] : 0.f);
}

// ---------------- Kz: zero logit accumulator ----------------
__global__ void zero_logit(float* __restrict__ logit) {
  int i = blockIdx.x * 256 + threadIdx.x;
  if (i < NTOK) logit[i] = 0.f;
}

// ---------------- K1: LN stats per token (two-pass in registers) ----------------
__global__ __launch_bounds__(256) void ln_stats(const float* __restrict__ x,
    float* __restrict__ mu, float* __restrict__ rs) {
  int token = blockIdx.x * 4 + (threadIdx.x >> 6);
  int lane = threadIdx.x & 63;
  const float4* xr = (const float4*)(x + (size_t)token * DIM_);
  float4 v[4];
  float sum = 0.f;
#pragma unroll
  for (int it = 0; it < 4; ++it) {
    v[it] = xr[lane + it * 64];
    sum += v[it].x + v[it].y + v[it].z + v[it].w;
  }
  for (int o = 32; o > 0; o >>= 1) sum += __shfl_xor(sum, o);
  float m = sum * (1.f / 1024.f);
  float ss = 0.f;
#pragma unroll
  for (int it = 0; it < 4; ++it) {
    float a = v[it].x - m, b = v[it].y - m, c = v[it].z - m, d = v[it].w - m;
    ss += a * a + b * b + c * c + d * d;
  }
  for (int o = 32; o > 0; o >>= 1) ss += __shfl_xor(ss, o);
  if (lane == 0) {
    mu[token] = m;
    rs[token] = 1.0f / sqrtf(ss * (1.f / 1024.f) + 1e-5f);
  }
}

// ---------------- K2: fused GEMM  C[32768x640] = x̂ @ Wcat + bias ----------------
// epilogue: cols<128 -> mbuf (raw m); cols>=128 -> relu, dot w_imp2, atomicAdd logit
__global__ __launch_bounds__(256) void gemm640(const float* __restrict__ x,
    const float* __restrict__ mu, const float* __restrict__ rs,
    const float* __restrict__ Wcat, const float* __restrict__ biascat,
    const float* __restrict__ w2, float* __restrict__ mbuf,
    float* __restrict__ logit) {
  __shared__ __align__(16) float As[16][68];
  __shared__ __align__(16) float Bs[16][68];
  const int tid = threadIdx.x;
  const int row0 = blockIdx.x * 64, col0 = blockIdx.y * 64;
  const int tx = tid & 15, ty = tid >> 4;
  const int arow = tid >> 2, akk = (tid & 3) << 2;
  const int brow = tid >> 4, bnn = (tid & 15) << 2;
  const int t_g = row0 + arow;
  const float tmu = mu[t_g], trs = rs[t_g];
  const float* xrow = x + (size_t)t_g * DIM_ + akk;
  const float* wptr = Wcat + (size_t)brow * NCAT + col0 + bnn;
  float acc[4][4] = {};
  for (int k0 = 0; k0 < DIM_; k0 += 16) {
    float4 av = *(const float4*)(xrow + k0);
    float4 bv = *(const float4*)(wptr + (size_t)k0 * NCAT);
    As[akk + 0][arow] = (av.x - tmu) * trs;
    As[akk + 1][arow] = (av.y - tmu) * trs;
    As[akk + 2][arow] = (av.z - tmu) * trs;
    As[akk + 3][arow] = (av.w - tmu) * trs;
    *(float4*)&Bs[brow][bnn] = bv;
    __syncthreads();
#pragma unroll
    for (int k = 0; k < 16; ++k) {
      float4 a = *(const float4*)&As[k][ty << 2];
      float4 b = *(const float4*)&Bs[k][tx << 2];
      acc[0][0] += a.x * b.x; acc[0][1] += a.x * b.y; acc[0][2] += a.x * b.z; acc[0][3] += a.x * b.w;
      acc[1][0] += a.y * b.x; acc[1][1] += a.y * b.y; acc[1][2] += a.y * b.z; acc[1][3] += a.y * b.w;
      acc[2][0] += a.z * b.x; acc[2][1] += a.z * b.y; acc[2][2] += a.z * b.z; acc[2][3] += a.z * b.w;
      acc[3][0] += a.w * b.x; acc[3][1] += a.w * b.y; acc[3][2] += a.w * b.z; acc[3][3] += a.w * b.w;
    }
    __syncthreads();
  }
  float bias[4];
#pragma unroll
  for (int j = 0; j < 4; ++j) bias[j] = biascat[col0 + (tx << 2) + j];
  if (col0 < MDIM_) {
#pragma unroll
    for (int i = 0; i < 4; ++i) {
      int t = row0 + (ty << 2) + i;
      float4 o;
      o.x = acc[i][0] + bias[0]; o.y = acc[i][1] + bias[1];
      o.z = acc[i][2] + bias[2]; o.w = acc[i][3] + bias[3];
      *(float4*)(mbuf + (size_t)t * MDIM_ + col0 + (tx << 2)) = o;
    }
  } else {
    float w2v[4];
#pragma unroll
    for (int j = 0; j < 4; ++j) w2v[j] = w2[col0 - MDIM_ + (tx << 2) + j];
#pragma unroll
    for (int i = 0; i < 4; ++i) {
      float p = 0.f;
#pragma unroll
      for (int j = 0; j < 4; ++j) {
        float v = acc[i][j] + bias[j];
        v = v > 0.f ? v : 0.f;
        p += v * w2v[j];
      }
      p += __shfl_xor(p, 1); p += __shfl_xor(p, 2);
      p += __shfl_xor(p, 4); p += __shfl_xor(p, 8);
      if (tx == 0) atomicAdd(&logit[row0 + (ty << 2) + i], p);
    }
  }
}

// ---------------- K3: L2-normalize each m row ----------------
__global__ __launch_bounds__(256) void norm_m(float* __restrict__ mbuf) {
  int token = blockIdx.x * 4 + (threadIdx.x >> 6);
  int lane = threadIdx.x & 63;
  float2* mr = (float2*)(mbuf + (size_t)token * MDIM_);
  float2 v = mr[lane];
  float ss = v.x * v.x + v.y * v.y;
  for (int o = 32; o > 0; o >>= 1) ss += __shfl_xor(ss, o);
  float inv = 1.0f / sqrtf(ss);
  v.x *= inv; v.y *= inv;
  mr[lane] = v;
}

// ---------------- K4: imp = sigmoid(logit + b_imp2) ----------------
__global__ void imp_kernel(const float* __restrict__ logit,
    const float* __restrict__ b2, float* __restrict__ imp) {
  int i = blockIdx.x * 256 + threadIdx.x;
  if (i < NTOK) {
    float z = logit[i] + b2[0];
    imp[i] = 1.f / (1.f + expf(-z));
  }
}

// ---------------- K5: per-window sim + greedy matching (one wave/window) ----------------
__global__ __launch_bounds__(256) void simgreedy(const float* __restrict__ mbuf,
    int* __restrict__ ii, int* __restrict__ jj, float* __restrict__ sv) {
  __shared__ __align__(16) float sm[4][16][132];
  int wv = threadIdx.x >> 6, lane = threadIdx.x & 63;
  int win = blockIdx.x * 4 + wv;
  int b = win >> 7, w = win & 127;
  size_t base = ((size_t)b * T_ + w * WINSZ) * MDIM_;
#pragma unroll
  for (int it = 0; it < 8; ++it) {
    int e4 = it * 64 + lane;      // 512 float4 = 16 rows x 32
    int row = e4 >> 5, c4 = e4 & 31;
    float4 v = *(const float4*)(mbuf + base + (size_t)row * MDIM_ + c4 * 4);
    *(float4*)&sm[wv][row][c4 * 4] = v;
  }
  __syncthreads();
  int a = lane >> 3, c = lane & 7;
  const float* ev = sm[wv][2 * a];
  const float* od = sm[wv][2 * c + 1];
  float s = 0.f;
#pragma unroll
  for (int k = 0; k < MDIM_; ++k) s += ev[k] * od[k];
  if (s < -10.0f) s = -__builtin_inff();
  float v = s;
  bool alive = true;
  int outb = (b * NW_ + w) * MAXP_;
  for (int p = 0; p < MAXP_; ++p) {
    float bv = alive ? v : -__builtin_inff();
    int bi = lane;
    for (int o = 32; o > 0; o >>= 1) {
      float ov = __shfl_xor(bv, o);
      int oi = __shfl_xor(bi, o);
      if (ov > bv || (ov == bv && oi < bi)) { bv = ov; bi = oi; }
    }
    int wa = bi >> 3, wc = bi & 7;
    if (lane == 0) {
      ii[outb + p] = w * WINSZ + 2 * wa;
      jj[outb + p] = w * WINSZ + 2 * wc + 1;
      sv[outb + p] = bv;
    }
    if (a == wa || c == wc) alive = false;
  }
}

// ---------------- K6: scores, exact stable top-k, alpha, rep/drop ----------------
__global__ __launch_bounds__(256) void select_kernel(const float* __restrict__ sv,
    const int* __restrict__ ii, const int* __restrict__ jj,
    const float* __restrict__ imp, float* __restrict__ alpha,
    int* __restrict__ rep, int* __restrict__ drop) {
  int b = blockIdx.x, tid = threadIdx.x;
  __shared__ float sc[P_];
  for (int t = tid; t < T_; t += 256) {
    rep[b * T_ + t] = -1;
    drop[b * T_ + t] = 0;
  }
  for (int p = tid; p < P_; p += 256) {
    int i = ii[b * P_ + p], j = jj[b * P_ + p];
    float fi = imp[b * T_ + i], fj = imp[b * T_ + j];
    sc[p] = sv[b * P_ + p] - 0.25f * (fi + fj);
    alpha[b * P_ + p] = 1.f / (1.f + expf(-5.f * (fi - fj)));
  }
  __syncthreads();
  for (int p = tid; p < P_; p += 256) {
    float s = sc[p];
    int cnt = 0;
    for (int q = 0; q < P_; ++q) {
      float t = sc[q];
      cnt += (t > s) || (t == s && q < p);
    }
    if (cnt < KDROP) {  // selected by top_k
      rep[b * T_ + ii[b * P_ + p]] = p;
      drop[b * T_ + jj[b * P_ + p]] = 1;
    }
  }
}

// ---------------- K7: per-batch exclusive prefix of keep mask ----------------
__global__ __launch_bounds__(64) void prefix_kernel(const int* __restrict__ drop,
    int* __restrict__ pos) {
  int b = blockIdx.x, lane = threadIdx.x;
  const int* dr = drop + b * T_;
  int t0 = lane * 32;
  int s = 0;
  for (int k = 0; k < 32; ++k) s += (dr[t0 + k] ? 0 : 1);
  int incl = s;
  for (int o = 1; o < 64; o <<= 1) {
    int n = __shfl_up(incl, o);
    if (lane >= o) incl += n;
  }
  int run = incl - s;
  int* ps = pos + b * T_;
  for (int k = 0; k < 32; ++k) {
    ps[t0 + k] = run;
    run += (dr[t0 + k] ? 0 : 1);
  }
}

// ---------------- K8: merge + pack copy-out ----------------
__global__ __launch_bounds__(256) void pack_kernel(const float* __restrict__ x,
    const int* __restrict__ drop, const int* __restrict__ pos,
    const int* __restrict__ rep, const float* __restrict__ alpha,
    const int* __restrict__ jj, float* __restrict__ out) {
  int t = blockIdx.x, b = blockIdx.y;
  if (drop[b * T_ + t]) return;
  int tid = threadIdx.x;
  const float4* xi = (const float4*)(x + ((size_t)b * T_ + t) * DIM_);
  float4 v = xi[tid];
  int p = rep[b * T_ + t];
  if (p >= 0) {
    float a = alpha[b * P_ + p];
    int j = jj[b * P_ + p];
    const float4* xj = (const float4*)(x + ((size_t)b * T_ + j) * DIM_);
    float4 vj = xj[tid];
    v.x = a * v.x + (1.f - a) * vj.x;
    v.y = a * v.y + (1.f - a) * vj.y;
    v.z = a * v.z + (1.f - a) * vj.z;
    v.w = a * v.w + (1.f - a) * vj.w;
  }
  int np = pos[b * T_ + t];
  ((float4*)(out + ((size_t)b * TKEEP + np) * DIM_))[tid] = v;
}

extern "C" void kernel_launch(void* const* d_in, const int* in_sizes, int n_in,
                              void* d_out, int out_size, void* d_ws, size_t ws_size,
                              hipStream_t stream) {
  const float* x    = (const float*)d_in[0];
  const float* gm   = (const float*)d_in[1];
  const float* bm   = (const float*)d_in[2];
  const float* wm   = (const float*)d_in[3];
  const float* gi   = (const float*)d_in[4];
  const float* bi   = (const float*)d_in[5];
  const float* wi   = (const float*)d_in[6];
  const float* b1   = (const float*)d_in[7];
  const float* w2   = (const float*)d_in[8];
  const float* b2   = (const float*)d_in[9];
  float* ws = (float*)d_ws;
  float* Wcat = ws + OFF_WCAT;
  float* bias = ws + OFF_BIAS;
  float* mu   = ws + OFF_MU;
  float* rs   = ws + OFF_RS;
  float* mbuf = ws + OFF_MBUF;
  float* logit = ws + OFF_LOGIT;
  float* imp  = ws + OFF_IMP;
  int* iidx   = (int*)(ws + OFF_IIDX);
  int* jidx   = (int*)(ws + OFF_JIDX);
  float* sv   = ws + OFF_SV;
  float* alpha = ws + OFF_ALPHA;
  int* rep    = (int*)(ws + OFF_REP);
  int* drop   = (int*)(ws + OFF_DROP);
  int* pos    = (int*)(ws + OFF_POS);
  float* out  = (float*)d_out;

  build_wcat<<<(DIM_ * NCAT + 255) / 256, 256, 0, stream>>>(wm, wi, gm, gi, Wcat);
  build_bias<<<NCAT, 256, 0, stream>>>(wm, wi, bm, bi, b1, bias);
  zero_logit<<<NTOK / 256, 256, 0, stream>>>(logit);
  ln_stats<<<NTOK / 4, 256, 0, stream>>>(x, mu, rs);
  dim3 ggrid(NTOK / 64, NCAT / 64);
  gemm640<<<ggrid, 256, 0, stream>>>(x, mu, rs, Wcat, bias, w2, mbuf, logit);
  norm_m<<<NTOK / 4, 256, 0, stream>>>(mbuf);
  imp_kernel<<<NTOK / 256, 256, 0, stream>>>(logit, b2, imp);
  simgreedy<<<(B_ * NW_) / 4, 256, 0, stream>>>(mbuf, iidx, jidx, sv);
  select_kernel<<<B_, 256, 0, stream>>>(sv, iidx, jidx, imp, alpha, rep, drop);
  prefix_kernel<<<B_, 64, 0, stream>>>(drop, pos);
  dim3 pgrid(T_, B_);
  pack_kernel<<<pgrid, 256, 0, stream>>>(x, drop, pos, rep, alpha, jidx, out);
}

// Round 2
// 573.516 us; speedup vs baseline: 1.6066x; 1.6066x over previous
//
#include <hip/hip_runtime.h>
#include <math.h>

#define B_ 16
#define T_ 2048
#define DIM_ 1024
#define MDIM_ 128
#define HID_ 512
#define NCAT 640
#define NW_ 128
#define WINSZ 16
#define MAXP_ 6
#define P_ 768
#define KDROP 614
#define TKEEP 1434
#define NTOK (B_*T_)

typedef unsigned short u16;
typedef __bf16 bf16x8 __attribute__((ext_vector_type(8)));
typedef float f32x4 __attribute__((ext_vector_type(4)));
typedef unsigned short us4 __attribute__((ext_vector_type(4)));

// ---------- old (fallback) workspace layout (float units) ----------
#define OFF_WCAT   0
#define OFF_BIAS   (OFF_WCAT + DIM_*NCAT)
#define OFF_MU     (OFF_BIAS + NCAT)
#define OFF_RS     (OFF_MU + NTOK)
#define OFF_MBUF   (OFF_RS + NTOK)
#define OFF_LOGIT  (OFF_MBUF + NTOK*MDIM_)
#define OFF_IMP    (OFF_LOGIT + NTOK)
#define OFF_IIDX   (OFF_IMP + NTOK)
#define OFF_JIDX   (OFF_IIDX + B_*P_)
#define OFF_SV     (OFF_JIDX + B_*P_)
#define OFF_ALPHA  (OFF_SV + B_*P_)
#define OFF_REP    (OFF_ALPHA + B_*P_)
#define OFF_DROP   (OFF_REP + NTOK)
#define OFF_POS    (OFF_DROP + NTOK)

// ---------- fast-path workspace layout (float units) ----------
static constexpr size_t F_AH    = 0;                                    // NTOK*DIM_ u16
static constexpr size_t F_AL    = F_AH + (size_t)NTOK*DIM_/2;
static constexpr size_t F_BH    = F_AL + (size_t)NTOK*DIM_/2;           // NCAT*DIM_ u16 (transposed)
static constexpr size_t F_BL    = F_BH + (size_t)NCAT*DIM_/2;
static constexpr size_t F_BIAS  = F_BL + (size_t)NCAT*DIM_/2;
static constexpr size_t F_MBUF  = F_BIAS + NCAT;
static constexpr size_t F_LOGIT = F_MBUF + (size_t)NTOK*MDIM_;
static constexpr size_t F_IMP   = F_LOGIT + NTOK;
static constexpr size_t F_IIDX  = F_IMP + NTOK;
static constexpr size_t F_JIDX  = F_IIDX + (size_t)B_*P_;
static constexpr size_t F_SV    = F_JIDX + (size_t)B_*P_;
static constexpr size_t F_ALPHA = F_SV + (size_t)B_*P_;
static constexpr size_t F_REP   = F_ALPHA + (size_t)B_*P_;
static constexpr size_t F_DROP  = F_REP + NTOK;
static constexpr size_t F_POS   = F_DROP + NTOK;
static constexpr size_t F_TOTAL = F_POS + NTOK;

// ---------------- helpers: exact RNE bf16 split (bit tricks, no header drift) ----------------
__device__ __forceinline__ u16 f2bf(float f) {
  unsigned u = __builtin_bit_cast(unsigned, f);
  unsigned r = u + 0x7FFFu + ((u >> 16) & 1u);
  return (u16)(r >> 16);
}
__device__ __forceinline__ float bf2f(u16 h) {
  unsigned u = ((unsigned)h) << 16;
  return __builtin_bit_cast(float, u);
}
__device__ __forceinline__ void gll16(const void* g, void* l) {
  __builtin_amdgcn_global_load_lds((const __attribute__((address_space(1))) void*)g,
                                   (__attribute__((address_space(3))) void*)l, 16, 0, 0);
}

// ================= fast path kernels =================

// prep_a: LN stats + x̂ + bf16 hi/lo split, one wave per token
__global__ __launch_bounds__(256) void prep_a(const float* __restrict__ x,
    u16* __restrict__ Ah, u16* __restrict__ Al) {
  int token = blockIdx.x * 4 + (threadIdx.x >> 6);
  int lane = threadIdx.x & 63;
  const float4* xr = (const float4*)(x + (size_t)token * DIM_);
  float4 v[4];
  float sum = 0.f;
#pragma unroll
  for (int it = 0; it < 4; ++it) {
    v[it] = xr[lane + it * 64];
    sum += v[it].x + v[it].y + v[it].z + v[it].w;
  }
  for (int o = 32; o > 0; o >>= 1) sum += __shfl_xor(sum, o);
  float m = sum * (1.f / 1024.f);
  float ss = 0.f;
#pragma unroll
  for (int it = 0; it < 4; ++it) {
    float a = v[it].x - m, b = v[it].y - m, c = v[it].z - m, d = v[it].w - m;
    ss += a * a + b * b + c * c + d * d;
  }
  for (int o = 32; o > 0; o >>= 1) ss += __shfl_xor(ss, o);
  float rsv = 1.0f / sqrtf(ss * (1.f / 1024.f) + 1e-5f);
#pragma unroll
  for (int it = 0; it < 4; ++it) {
    float e[4] = {(v[it].x - m) * rsv, (v[it].y - m) * rsv,
                  (v[it].z - m) * rsv, (v[it].w - m) * rsv};
    us4 hv, lv;
#pragma unroll
    for (int j = 0; j < 4; ++j) {
      u16 h = f2bf(e[j]);
      hv[j] = h;
      lv[j] = f2bf(e[j] - bf2f(h));
    }
    size_t off = (size_t)token * DIM_ + (size_t)(lane + it * 64) * 4;
    *(us4*)&Ah[off] = hv;
    *(us4*)&Al[off] = lv;
  }
}

// prep_b: Bt[n][k] = g[k]*W[k][n], split hi/lo, transposed (k-contiguous)
__global__ __launch_bounds__(256) void prep_b(const float* __restrict__ wm,
    const float* __restrict__ wi, const float* __restrict__ gm,
    const float* __restrict__ gi, u16* __restrict__ Bh, u16* __restrict__ Bl) {
  int e = blockIdx.x * 256 + threadIdx.x;  // n*1024 + k
  if (e >= NCAT * DIM_) return;
  int n = e >> 10, k = e & 1023;
  float wv = (n < MDIM_) ? gm[k] * wm[k * MDIM_ + n]
                         : gi[k] * wi[k * HID_ + (n - MDIM_)];
  u16 h = f2bf(wv);
  Bh[e] = h;
  Bl[e] = f2bf(wv - bf2f(h));
}

// gemm_mfma: C[32768x640] = (Ah+Al)@(Bh+Bl)^T via 3-product bf16 MFMA
// tile 128x128, BK=32, frag-contiguous LDS, global_load_lds width=16
__global__ __launch_bounds__(256, 2) void gemm_mfma(
    const u16* __restrict__ Ah, const u16* __restrict__ Al,
    const u16* __restrict__ Bh, const u16* __restrict__ Bl,
    const float* __restrict__ biascat, const float* __restrict__ w2,
    float* __restrict__ mbuf, float* __restrict__ logit) {
  __shared__ __align__(16) u16 sAH[8 * 512];
  __shared__ __align__(16) u16 sAL[8 * 512];
  __shared__ __align__(16) u16 sBH[8 * 512];
  __shared__ __align__(16) u16 sBL[8 * 512];
  const int tid = threadIdx.x;
  const int w = tid >> 6, lane = tid & 63;
  // XCD-aware swizzle: 5 col-tiles of a row-stripe share one XCD (ids ≡ mod 8)
  int bid = blockIdx.x;
  int q = bid / 40, rem = bid % 40;
  int ct = rem >> 3, x8 = rem & 7;
  int stripe = x8 + 8 * q;
  const int row0 = stripe * 128, col0 = ct * 128;
  const int wy = w >> 1, wx = w & 1;
  const int m16 = lane & 15, quad = lane >> 4;

  // staging duty: wave0->AH, wave1->AL, wave2->BH, wave3->BL (8 tiles each)
  const u16* gA = (w == 0) ? Ah : (w == 1) ? Al : (w == 2) ? Bh : Bl;
  u16* lds0 = ((w == 0) ? sAH : (w == 1) ? sAL : (w == 2) ? sBH : sBL) + lane * 8;
  const int rbase = (w < 2) ? row0 : col0;
  const u16* gsrc0 = gA + (size_t)(rbase + m16) * DIM_ + quad * 8;

  f32x4 acc[4][4] = {};
  for (int k0 = 0; k0 < DIM_; k0 += 32) {
    __syncthreads();  // prior compute done before LDS overwrite
#pragma unroll
    for (int t = 0; t < 8; ++t)
      gll16(gsrc0 + (size_t)t * 16 * DIM_ + k0, lds0 + t * 512);
    __syncthreads();  // staging visible
    bf16x8 ah[4], al[4], bh[4], bl[4];
#pragma unroll
    for (int i = 0; i < 4; ++i) {
      ah[i] = *(const bf16x8*)&sAH[(wy * 4 + i) * 512 + lane * 8];
      al[i] = *(const bf16x8*)&sAL[(wy * 4 + i) * 512 + lane * 8];
      bh[i] = *(const bf16x8*)&sBH[(wx * 4 + i) * 512 + lane * 8];
      bl[i] = *(const bf16x8*)&sBL[(wx * 4 + i) * 512 + lane * 8];
    }
#pragma unroll
    for (int i = 0; i < 4; ++i)
#pragma unroll
      for (int j = 0; j < 4; ++j) {
        acc[i][j] = __builtin_amdgcn_mfma_f32_16x16x32_bf16(ah[i], bh[j], acc[i][j], 0, 0, 0);
        acc[i][j] = __builtin_amdgcn_mfma_f32_16x16x32_bf16(ah[i], bl[j], acc[i][j], 0, 0, 0);
        acc[i][j] = __builtin_amdgcn_mfma_f32_16x16x32_bf16(al[i], bh[j], acc[i][j], 0, 0, 0);
      }
  }
  // epilogue: C/D layout col=lane&15 (n), row=quad*4+r (m)
  if (ct == 0) {
#pragma unroll
    for (int i = 0; i < 4; ++i)
#pragma unroll
      for (int j = 0; j < 4; ++j) {
        int col = wx * 64 + j * 16 + m16;
        float bs = biascat[col];
#pragma unroll
        for (int r = 0; r < 4; ++r) {
          int row = row0 + wy * 64 + i * 16 + quad * 4 + r;
          mbuf[(size_t)row * MDIM_ + col] = acc[i][j][r] + bs;
        }
      }
  } else {
#pragma unroll
    for (int i = 0; i < 4; ++i) {
      float part[4] = {0.f, 0.f, 0.f, 0.f};
#pragma unroll
      for (int j = 0; j < 4; ++j) {
        int col = col0 + wx * 64 + j * 16 + m16;
        float bs = biascat[col];
        float wv = w2[col - MDIM_];
#pragma unroll
        for (int r = 0; r < 4; ++r) {
          float v = acc[i][j][r] + bs;
          v = v > 0.f ? v : 0.f;
          part[r] += v * wv;
        }
      }
#pragma unroll
      for (int r = 0; r < 4; ++r) {
        part[r] += __shfl_xor(part[r], 1);
        part[r] += __shfl_xor(part[r], 2);
        part[r] += __shfl_xor(part[r], 4);
        part[r] += __shfl_xor(part[r], 8);
      }
      if (m16 == 0)
#pragma unroll
        for (int r = 0; r < 4; ++r)
          atomicAdd(&logit[row0 + wy * 64 + i * 16 + quad * 4 + r], part[r]);
    }
  }
}

// ================= shared kernels (both paths) =================

__global__ __launch_bounds__(256) void build_bias(const float* __restrict__ wm,
    const float* __restrict__ wi, const float* __restrict__ bm,
    const float* __restrict__ bi, const float* __restrict__ b1,
    float* __restrict__ biascat) {
  int c = blockIdx.x;
  float s = 0.f;
  for (int k = threadIdx.x; k < DIM_; k += 256)
    s += (c < MDIM_) ? bm[k] * wm[k * MDIM_ + c]
                     : bi[k] * wi[k * HID_ + (c - MDIM_)];
  __shared__ float red[256];
  red[threadIdx.x] = s; __syncthreads();
  for (int o = 128; o > 0; o >>= 1) {
    if (threadIdx.x < o) red[threadIdx.x] += red[threadIdx.x + o];
    __syncthreads();
  }
  if (threadIdx.x == 0)
    biascat[c] = red[0] + ((c >= MDIM_) ? b1[c - MDIM_] : 0.f);
}

__global__ void zero_logit(float* __restrict__ logit) {
  int i = blockIdx.x * 256 + threadIdx.x;
  if (i < NTOK) logit[i] = 0.f;
}

__global__ __launch_bounds__(256) void norm_m(float* __restrict__ mbuf) {
  int token = blockIdx.x * 4 + (threadIdx.x >> 6);
  int lane = threadIdx.x & 63;
  float2* mr = (float2*)(mbuf + (size_t)token * MDIM_);
  float2 v = mr[lane];
  float ss = v.x * v.x + v.y * v.y;
  for (int o = 32; o > 0; o >>= 1) ss += __shfl_xor(ss, o);
  float inv = 1.0f / sqrtf(ss);
  v.x *= inv; v.y *= inv;
  mr[lane] = v;
}

__global__ void imp_kernel(const float* __restrict__ logit,
    const float* __restrict__ b2, float* __restrict__ imp) {
  int i = blockIdx.x * 256 + threadIdx.x;
  if (i < NTOK) {
    float z = logit[i] + b2[0];
    imp[i] = 1.f / (1.f + expf(-z));
  }
}

__global__ __launch_bounds__(256) void simgreedy(const float* __restrict__ mbuf,
    int* __restrict__ ii, int* __restrict__ jj, float* __restrict__ sv) {
  __shared__ __align__(16) float sm[4][16][132];
  int wv = threadIdx.x >> 6, lane = threadIdx.x & 63;
  int win = blockIdx.x * 4 + wv;
  int b = win >> 7, w = win & 127;
  size_t base = ((size_t)b * T_ + w * WINSZ) * MDIM_;
#pragma unroll
  for (int it = 0; it < 8; ++it) {
    int e4 = it * 64 + lane;
    int row = e4 >> 5, c4 = e4 & 31;
    float4 v = *(const float4*)(mbuf + base + (size_t)row * MDIM_ + c4 * 4);
    *(float4*)&sm[wv][row][c4 * 4] = v;
  }
  __syncthreads();
  int a = lane >> 3, c = lane & 7;
  const float* ev = sm[wv][2 * a];
  const float* od = sm[wv][2 * c + 1];
  float s = 0.f;
#pragma unroll
  for (int k = 0; k < MDIM_; ++k) s += ev[k] * od[k];
  if (s < -10.0f) s = -__builtin_inff();
  float v = s;
  bool alive = true;
  int outb = (b * NW_ + w) * MAXP_;
  for (int p = 0; p < MAXP_; ++p) {
    float bv = alive ? v : -__builtin_inff();
    int bi = lane;
    for (int o = 32; o > 0; o >>= 1) {
      float ov = __shfl_xor(bv, o);
      int oi = __shfl_xor(bi, o);
      if (ov > bv || (ov == bv && oi < bi)) { bv = ov; bi = oi; }
    }
    int wa = bi >> 3, wc = bi & 7;
    if (lane == 0) {
      ii[outb + p] = w * WINSZ + 2 * wa;
      jj[outb + p] = w * WINSZ + 2 * wc + 1;
      sv[outb + p] = bv;
    }
    if (a == wa || c == wc) alive = false;
  }
}

__global__ __launch_bounds__(256) void select_kernel(const float* __restrict__ sv,
    const int* __restrict__ ii, const int* __restrict__ jj,
    const float* __restrict__ imp, float* __restrict__ alpha,
    int* __restrict__ rep, int* __restrict__ drop) {
  int b = blockIdx.x, tid = threadIdx.x;
  __shared__ float sc[P_];
  for (int t = tid; t < T_; t += 256) {
    rep[b * T_ + t] = -1;
    drop[b * T_ + t] = 0;
  }
  for (int p = tid; p < P_; p += 256) {
    int i = ii[b * P_ + p], j = jj[b * P_ + p];
    float fi = imp[b * T_ + i], fj = imp[b * T_ + j];
    sc[p] = sv[b * P_ + p] - 0.25f * (fi + fj);
    alpha[b * P_ + p] = 1.f / (1.f + expf(-5.f * (fi - fj)));
  }
  __syncthreads();
  for (int p = tid; p < P_; p += 256) {
    float s = sc[p];
    int cnt = 0;
    for (int q = 0; q < P_; ++q) {
      float t = sc[q];
      cnt += (t > s) || (t == s && q < p);
    }
    if (cnt < KDROP) {
      rep[b * T_ + ii[b * P_ + p]] = p;
      drop[b * T_ + jj[b * P_ + p]] = 1;
    }
  }
}

__global__ __launch_bounds__(64) void prefix_kernel(const int* __restrict__ drop,
    int* __restrict__ pos) {
  int b = blockIdx.x, lane = threadIdx.x;
  const int* dr = drop + b * T_;
  int t0 = lane * 32;
  int s = 0;
  for (int k = 0; k < 32; ++k) s += (dr[t0 + k] ? 0 : 1);
  int incl = s;
  for (int o = 1; o < 64; o <<= 1) {
    int n = __shfl_up(incl, o);
    if (lane >= o) incl += n;
  }
  int run = incl - s;
  int* ps = pos + b * T_;
  for (int k = 0; k < 32; ++k) {
    ps[t0 + k] = run;
    run += (dr[t0 + k] ? 0 : 1);
  }
}

__global__ __launch_bounds__(256) void pack_kernel(const float* __restrict__ x,
    const int* __restrict__ drop, const int* __restrict__ pos,
    const int* __restrict__ rep, const float* __restrict__ alpha,
    const int* __restrict__ jj, float* __restrict__ out) {
  int t = blockIdx.x, b = blockIdx.y;
  if (drop[b * T_ + t]) return;
  int tid = threadIdx.x;
  const float4* xi = (const float4*)(x + ((size_t)b * T_ + t) * DIM_);
  float4 v = xi[tid];
  int p = rep[b * T_ + t];
  if (p >= 0) {
    float a = alpha[b * P_ + p];
    int j = jj[b * P_ + p];
    const float4* xj = (const float4*)(x + ((size_t)b * T_ + j) * DIM_);
    float4 vj = xj[tid];
    v.x = a * v.x + (1.f - a) * vj.x;
    v.y = a * v.y + (1.f - a) * vj.y;
    v.z = a * v.z + (1.f - a) * vj.z;
    v.w = a * v.w + (1.f - a) * vj.w;
  }
  int np = pos[b * T_ + t];
  ((float4*)(out + ((size_t)b * TKEEP + np) * DIM_))[tid] = v;
}

// ================= fallback fp32 GEMM path (round-1, proven) =================

__global__ __launch_bounds__(256) void build_wcat(const float* __restrict__ wm,
    const float* __restrict__ wi, const float* __restrict__ gm,
    const float* __restrict__ gi, float* __restrict__ Wcat) {
  int e = blockIdx.x * 256 + threadIdx.x;
  if (e >= DIM_ * NCAT) return;
  int k = e / NCAT, c = e - k * NCAT;
  float v = (c < MDIM_) ? gm[k] * wm[k * MDIM_ + c]
                        : gi[k] * wi[k * HID_ + (c - MDIM_)];
  Wcat[e] = v;
}

__global__ __launch_bounds__(256) void ln_stats(const float* __restrict__ x,
    float* __restrict__ mu, float* __restrict__ rs) {
  int token = blockIdx.x * 4 + (threadIdx.x >> 6);
  int lane = threadIdx.x & 63;
  const float4* xr = (const float4*)(x + (size_t)token * DIM_);
  float4 v[4];
  float sum = 0.f;
#pragma unroll
  for (int it = 0; it < 4; ++it) {
    v[it] = xr[lane + it * 64];
    sum += v[it].x + v[it].y + v[it].z + v[it].w;
  }
  for (int o = 32; o > 0; o >>= 1) sum += __shfl_xor(sum, o);
  float m = sum * (1.f / 1024.f);
  float ss = 0.f;
#pragma unroll
  for (int it = 0; it < 4; ++it) {
    float a = v[it].x - m, b = v[it].y - m, c = v[it].z - m, d = v[it].w - m;
    ss += a * a + b * b + c * c + d * d;
  }
  for (int o = 32; o > 0; o >>= 1) ss += __shfl_xor(ss, o);
  if (lane == 0) {
    mu[token] = m;
    rs[token] = 1.0f / sqrtf(ss * (1.f / 1024.f) + 1e-5f);
  }
}

__global__ __launch_bounds__(256) void gemm640(const float* __restrict__ x,
    const float* __restrict__ mu, const float* __restrict__ rs,
    const float* __restrict__ Wcat, const float* __restrict__ biascat,
    const float* __restrict__ w2, float* __restrict__ mbuf,
    float* __restrict__ logit) {
  __shared__ __align__(16) float As[16][68];
  __shared__ __align__(16) float Bs[16][68];
  const int tid = threadIdx.x;
  const int row0 = blockIdx.x * 64, col0 = blockIdx.y * 64;
  const int tx = tid & 15, ty = tid >> 4;
  const int arow = tid >> 2, akk = (tid & 3) << 2;
  const int brow = tid >> 4, bnn = (tid & 15) << 2;
  const int t_g = row0 + arow;
  const float tmu = mu[t_g], trs = rs[t_g];
  const float* xrow = x + (size_t)t_g * DIM_ + akk;
  const float* wptr = Wcat + (size_t)brow * NCAT + col0 + bnn;
  float acc[4][4] = {};
  for (int k0 = 0; k0 < DIM_; k0 += 16) {
    float4 av = *(const float4*)(xrow + k0);
    float4 bv = *(const float4*)(wptr + (size_t)k0 * NCAT);
    As[akk + 0][arow] = (av.x - tmu) * trs;
    As[akk + 1][arow] = (av.y - tmu) * trs;
    As[akk + 2][arow] = (av.z - tmu) * trs;
    As[akk + 3][arow] = (av.w - tmu) * trs;
    *(float4*)&Bs[brow][bnn] = bv;
    __syncthreads();
#pragma unroll
    for (int k = 0; k < 16; ++k) {
      float4 a = *(const float4*)&As[k][ty << 2];
      float4 b = *(const float4*)&Bs[k][tx << 2];
      acc[0][0] += a.x * b.x; acc[0][1] += a.x * b.y; acc[0][2] += a.x * b.z; acc[0][3] += a.x * b.w;
      acc[1][0] += a.y * b.x; acc[1][1] += a.y * b.y; acc[1][2] += a.y * b.z; acc[1][3] += a.y * b.w;
      acc[2][0] += a.z * b.x; acc[2][1] += a.z * b.y; acc[2][2] += a.z * b.z; acc[2][3] += a.z * b.w;
      acc[3][0] += a.w * b.x; acc[3][1] += a.w * b.y; acc[3][2] += a.w * b.z; acc[3][3] += a.w * b.w;
    }
    __syncthreads();
  }
  float bias[4];
#pragma unroll
  for (int j = 0; j < 4; ++j) bias[j] = biascat[col0 + (tx << 2) + j];
  if (col0 < MDIM_) {
#pragma unroll
    for (int i = 0; i < 4; ++i) {
      int t = row0 + (ty << 2) + i;
      float4 o;
      o.x = acc[i][0] + bias[0]; o.y = acc[i][1] + bias[1];
      o.z = acc[i][2] + bias[2]; o.w = acc[i][3] + bias[3];
      *(float4*)(mbuf + (size_t)t * MDIM_ + col0 + (tx << 2)) = o;
    }
  } else {
    float w2v[4];
#pragma unroll
    for (int j = 0; j < 4; ++j) w2v[j] = w2[col0 - MDIM_ + (tx << 2) + j];
#pragma unroll
    for (int i = 0; i < 4; ++i) {
      float p = 0.f;
#pragma unroll
      for (int j = 0; j < 4; ++j) {
        float v = acc[i][j] + bias[j];
        v = v > 0.f ? v : 0.f;
        p += v * w2v[j];
      }
      p += __shfl_xor(p, 1); p += __shfl_xor(p, 2);
      p += __shfl_xor(p, 4); p += __shfl_xor(p, 8);
      if (tx == 0) atomicAdd(&logit[row0 + (ty << 2) + i], p);
    }
  }
}

extern "C" void kernel_launch(void* const* d_in, const int* in_sizes, int n_in,
                              void* d_out, int out_size, void* d_ws, size_t ws_size,
                              hipStream_t stream) {
  const float* x    = (const float*)d_in[0];
  const float* gm   = (const float*)d_in[1];
  const float* bm   = (const float*)d_in[2];
  const float* wm   = (const float*)d_in[3];
  const float* gi   = (const float*)d_in[4];
  const float* bi   = (const float*)d_in[5];
  const float* wi   = (const float*)d_in[6];
  const float* b1   = (const float*)d_in[7];
  const float* w2   = (const float*)d_in[8];
  const float* b2   = (const float*)d_in[9];
  float* ws = (float*)d_ws;
  float* out = (float*)d_out;

  if (ws_size >= F_TOTAL * sizeof(float)) {
    // -------- fast path: bf16x2-split MFMA GEMM --------
    u16* Ah = (u16*)(ws + F_AH);
    u16* Al = (u16*)(ws + F_AL);
    u16* Bh = (u16*)(ws + F_BH);
    u16* Bl = (u16*)(ws + F_BL);
    float* bias  = ws + F_BIAS;
    float* mbuf  = ws + F_MBUF;
    float* logit = ws + F_LOGIT;
    float* imp   = ws + F_IMP;
    int* iidx    = (int*)(ws + F_IIDX);
    int* jidx    = (int*)(ws + F_JIDX);
    float* sv    = ws + F_SV;
    float* alpha = ws + F_ALPHA;
    int* rep     = (int*)(ws + F_REP);
    int* drop    = (int*)(ws + F_DROP);
    int* pos     = (int*)(ws + F_POS);

    prep_b<<<(NCAT * DIM_ + 255) / 256, 256, 0, stream>>>(wm, wi, gm, gi, Bh, Bl);
    build_bias<<<NCAT, 256, 0, stream>>>(wm, wi, bm, bi, b1, bias);
    zero_logit<<<NTOK / 256, 256, 0, stream>>>(logit);
    prep_a<<<NTOK / 4, 256, 0, stream>>>(x, Ah, Al);
    gemm_mfma<<<(NTOK / 128) * (NCAT / 128), 256, 0, stream>>>(Ah, Al, Bh, Bl, bias, w2, mbuf, logit);
    norm_m<<<NTOK / 4, 256, 0, stream>>>(mbuf);
    imp_kernel<<<NTOK / 256, 256, 0, stream>>>(logit, b2, imp);
    simgreedy<<<(B_ * NW_) / 4, 256, 0, stream>>>(mbuf, iidx, jidx, sv);
    select_kernel<<<B_, 256, 0, stream>>>(sv, iidx, jidx, imp, alpha, rep, drop);
    prefix_kernel<<<B_, 64, 0, stream>>>(drop, pos);
    dim3 pgrid(T_, B_);
    pack_kernel<<<pgrid, 256, 0, stream>>>(x, drop, pos, rep, alpha, jidx, out);
  } else {
    // -------- fallback: round-1 fp32 path --------
    float* Wcat = ws + OFF_WCAT;
    float* bias = ws + OFF_BIAS;
    float* mu   = ws + OFF_MU;
    float* rs   = ws + OFF_RS;
    float* mbuf = ws + OFF_MBUF;
    float* logit = ws + OFF_LOGIT;
    float* imp  = ws + OFF_IMP;
    int* iidx   = (int*)(ws + OFF_IIDX);
    int* jidx   = (int*)(ws + OFF_JIDX);
    float* sv   = ws + OFF_SV;
    float* alpha = ws + OFF_ALPHA;
    int* rep    = (int*)(ws + OFF_REP);
    int* drop   = (int*)(ws + OFF_DROP);
    int* pos    = (int*)(ws + OFF_POS);

    build_wcat<<<(DIM_ * NCAT + 255) / 256, 256, 0, stream>>>(wm, wi, gm, gi, Wcat);
    build_bias<<<NCAT, 256, 0, stream>>>(wm, wi, bm, bi, b1, bias);
    zero_logit<<<NTOK / 256, 256, 0, stream>>>(logit);
    ln_stats<<<NTOK / 4, 256, 0, stream>>>(x, mu, rs);
    dim3 ggrid(NTOK / 64, NCAT / 64);
    gemm640<<<ggrid, 256, 0, stream>>>(x, mu, rs, Wcat, bias, w2, mbuf, logit);
    norm_m<<<NTOK / 4, 256, 0, stream>>>(mbuf);
    imp_kernel<<<NTOK / 256, 256, 0, stream>>>(logit, b2, imp);
    simgreedy<<<(B_ * NW_) / 4, 256, 0, stream>>>(mbuf, iidx, jidx, sv);
    select_kernel<<<B_, 256, 0, stream>>>(sv, iidx, jidx, imp, alpha, rep, drop);
    prefix_kernel<<<B_, 64, 0, stream>>>(drop, pos);
    dim3 pgrid(T_, B_);
    pack_kernel<<<pgrid, 256, 0, stream>>>(x, drop, pos, rep, alpha, jidx, out);
  }
}

// Round 3
// 531.238 us; speedup vs baseline: 1.7345x; 1.0796x over previous
//
#include <hip/hip_runtime.h>
#include <math.h>

#define B_ 16
#define T_ 2048
#define DIM_ 1024
#define MDIM_ 128
#define HID_ 512
#define NCAT 640
#define NW_ 128
#define WINSZ 16
#define MAXP_ 6
#define P_ 768
#define KDROP 614
#define TKEEP 1434
#define NTOK (B_*T_)

typedef unsigned short u16;
typedef __bf16 bf16x8 __attribute__((ext_vector_type(8)));
typedef float f32x4 __attribute__((ext_vector_type(4)));
typedef unsigned short us4 __attribute__((ext_vector_type(4)));

// ---------- fallback (fp32) workspace layout (float units) ----------
#define OFF_WCAT   0
#define OFF_BIAS   (OFF_WCAT + DIM_*NCAT)
#define OFF_MU     (OFF_BIAS + NCAT)
#define OFF_RS     (OFF_MU + NTOK)
#define OFF_MBUF   (OFF_RS + NTOK)
#define OFF_LOGIT  (OFF_MBUF + NTOK*MDIM_)
#define OFF_IIDX   (OFF_LOGIT + NTOK)
#define OFF_JIDX   (OFF_IIDX + B_*P_)
#define OFF_SV     (OFF_JIDX + B_*P_)
#define OFF_ALPHA  (OFF_SV + B_*P_)
#define OFF_REP    (OFF_ALPHA + B_*P_)
#define OFF_DROP   (OFF_REP + NTOK)
#define OFF_POS    (OFF_DROP + NTOK)

// ---------- fast-path workspace layout (float units) ----------
static constexpr size_t F_AH    = 0;                                    // NTOK*DIM_ u16
static constexpr size_t F_AL    = F_AH + (size_t)NTOK*DIM_/2;
static constexpr size_t F_BH    = F_AL + (size_t)NTOK*DIM_/2;           // NCAT*DIM_ u16 (transposed)
static constexpr size_t F_BL    = F_BH + (size_t)NCAT*DIM_/2;
static constexpr size_t F_BIAS  = F_BL + (size_t)NCAT*DIM_/2;
static constexpr size_t F_MBUF  = F_BIAS + NCAT;
static constexpr size_t F_LOGIT = F_MBUF + (size_t)NTOK*MDIM_;
static constexpr size_t F_IIDX  = F_LOGIT + NTOK;
static constexpr size_t F_JIDX  = F_IIDX + (size_t)B_*P_;
static constexpr size_t F_SV    = F_JIDX + (size_t)B_*P_;
static constexpr size_t F_ALPHA = F_SV + (size_t)B_*P_;
static constexpr size_t F_REP   = F_ALPHA + (size_t)B_*P_;
static constexpr size_t F_DROP  = F_REP + NTOK;
static constexpr size_t F_POS   = F_DROP + NTOK;
static constexpr size_t F_TOTAL = F_POS + NTOK;

// ---------------- helpers ----------------
__device__ __forceinline__ u16 f2bf(float f) {
  unsigned u = __builtin_bit_cast(unsigned, f);
  unsigned r = u + 0x7FFFu + ((u >> 16) & 1u);
  return (u16)(r >> 16);
}
__device__ __forceinline__ float bf2f(u16 h) {
  unsigned u = ((unsigned)h) << 16;
  return __builtin_bit_cast(float, u);
}
__device__ __forceinline__ void gll16(const void* g, void* l) {
  __builtin_amdgcn_global_load_lds((const __attribute__((address_space(1))) void*)g,
                                   (__attribute__((address_space(3))) void*)l, 16, 0, 0);
}

// ================= fast path kernels =================

// prep_a: LN stats + x-hat + bf16 hi/lo split, one wave per token
__global__ __launch_bounds__(256) void prep_a(const float* __restrict__ x,
    u16* __restrict__ Ah, u16* __restrict__ Al) {
  int token = blockIdx.x * 4 + (threadIdx.x >> 6);
  int lane = threadIdx.x & 63;
  const float4* xr = (const float4*)(x + (size_t)token * DIM_);
  float4 v[4];
  float sum = 0.f;
#pragma unroll
  for (int it = 0; it < 4; ++it) {
    v[it] = xr[lane + it * 64];
    sum += v[it].x + v[it].y + v[it].z + v[it].w;
  }
  for (int o = 32; o > 0; o >>= 1) sum += __shfl_xor(sum, o);
  float m = sum * (1.f / 1024.f);
  float ss = 0.f;
#pragma unroll
  for (int it = 0; it < 4; ++it) {
    float a = v[it].x - m, b = v[it].y - m, c = v[it].z - m, d = v[it].w - m;
    ss += a * a + b * b + c * c + d * d;
  }
  for (int o = 32; o > 0; o >>= 1) ss += __shfl_xor(ss, o);
  float rsv = 1.0f / sqrtf(ss * (1.f / 1024.f) + 1e-5f);
#pragma unroll
  for (int it = 0; it < 4; ++it) {
    float e[4] = {(v[it].x - m) * rsv, (v[it].y - m) * rsv,
                  (v[it].z - m) * rsv, (v[it].w - m) * rsv};
    us4 hv, lv;
#pragma unroll
    for (int j = 0; j < 4; ++j) {
      u16 h = f2bf(e[j]);
      hv[j] = h;
      lv[j] = f2bf(e[j] - bf2f(h));
    }
    size_t off = (size_t)token * DIM_ + (size_t)(lane + it * 64) * 4;
    *(us4*)&Ah[off] = hv;
    *(us4*)&Al[off] = lv;
  }
}

// prep_w: fused prep_b (Bt split hi/lo) + bias projection
__global__ __launch_bounds__(256) void prep_w(const float* __restrict__ wm,
    const float* __restrict__ wi, const float* __restrict__ gm,
    const float* __restrict__ gi, const float* __restrict__ bm,
    const float* __restrict__ bi, const float* __restrict__ b1,
    u16* __restrict__ Bh, u16* __restrict__ Bl, float* __restrict__ biascat) {
  int bid = blockIdx.x;
  const int NBLK_B = (NCAT * DIM_) / 256;
  if (bid < NBLK_B) {
    int e = bid * 256 + threadIdx.x;  // n*1024 + k
    int n = e >> 10, k = e & 1023;
    float wv = (n < MDIM_) ? gm[k] * wm[k * MDIM_ + n]
                           : gi[k] * wi[k * HID_ + (n - MDIM_)];
    u16 h = f2bf(wv);
    Bh[e] = h;
    Bl[e] = f2bf(wv - bf2f(h));
  } else {
    int c = bid - NBLK_B;
    float s = 0.f;
    for (int k = threadIdx.x; k < DIM_; k += 256)
      s += (c < MDIM_) ? bm[k] * wm[k * MDIM_ + c]
                       : bi[k] * wi[k * HID_ + (c - MDIM_)];
    __shared__ float red[256];
    red[threadIdx.x] = s; __syncthreads();
    for (int o = 128; o > 0; o >>= 1) {
      if (threadIdx.x < o) red[threadIdx.x] += red[threadIdx.x + o];
      __syncthreads();
    }
    if (threadIdx.x == 0)
      biascat[c] = red[0] + ((c >= MDIM_) ? b1[c - MDIM_] : 0.f);
  }
}

// gemm_mfma: C[32768x640] = (Ah+Al)@(Bh+Bl)^T via 3-product bf16 MFMA
// 128x128 tile, BK=32, DOUBLE-BUFFERED LDS: prefetch k+1 issued before compute
// of k, so ~1000 cyc of MFMA+ds_read hides the load latency at the barrier.
__global__ __launch_bounds__(256, 2) void gemm_mfma(
    const u16* __restrict__ Ah, const u16* __restrict__ Al,
    const u16* __restrict__ Bh, const u16* __restrict__ Bl,
    const float* __restrict__ biascat, const float* __restrict__ w2,
    float* __restrict__ mbuf, float* __restrict__ logit) {
  __shared__ __align__(16) u16 sAH[2][8 * 512];
  __shared__ __align__(16) u16 sAL[2][8 * 512];
  __shared__ __align__(16) u16 sBH[2][8 * 512];
  __shared__ __align__(16) u16 sBL[2][8 * 512];
  const int tid = threadIdx.x;
  const int w = tid >> 6, lane = tid & 63;
  // XCD-aware swizzle: 5 col-tiles of a row-stripe share one XCD (ids == mod 8)
  int bid = blockIdx.x;
  int q = bid / 40, rem = bid % 40;
  int ct = rem >> 3, x8 = rem & 7;
  int stripe = x8 + 8 * q;
  const int row0 = stripe * 128, col0 = ct * 128;
  const int wy = w >> 1, wx = w & 1;
  const int m16 = lane & 15, quad = lane >> 4;

  // staging duty: wave0->AH, wave1->AL, wave2->BH, wave3->BL (8 tiles each)
  const u16* gA = (w == 0) ? Ah : (w == 1) ? Al : (w == 2) ? Bh : Bl;
  u16* lds0 = ((w == 0) ? sAH[0] : (w == 1) ? sAL[0] : (w == 2) ? sBH[0] : sBL[0]) + lane * 8;
  u16* lds1 = ((w == 0) ? sAH[1] : (w == 1) ? sAL[1] : (w == 2) ? sBH[1] : sBL[1]) + lane * 8;
  const int rbase = (w < 2) ? row0 : col0;
  const u16* gsrc0 = gA + (size_t)(rbase + m16) * DIM_ + quad * 8;

  // preload k-step 0 into buffer 0
#pragma unroll
  for (int t = 0; t < 8; ++t)
    gll16(gsrc0 + (size_t)t * 16 * DIM_, lds0 + t * 512);

  f32x4 acc[4][4] = {};
  for (int k0 = 0; k0 < 32; ++k0) {
    __syncthreads();  // drains vmcnt -> buf[k0&1] staged; prev reads of other buf done
    if (k0 + 1 < 32) {
      u16* nb = (k0 & 1) ? lds0 : lds1;   // next buffer index = (k0+1)&1
#pragma unroll
      for (int t = 0; t < 8; ++t)
        gll16(gsrc0 + (size_t)t * 16 * DIM_ + (k0 + 1) * 32, nb + t * 512);
    }
    const int cb = k0 & 1;
    bf16x8 ah[4], al[4], bh[4], bl[4];
#pragma unroll
    for (int i = 0; i < 4; ++i) {
      ah[i] = *(const bf16x8*)&sAH[cb][(wy * 4 + i) * 512 + lane * 8];
      al[i] = *(const bf16x8*)&sAL[cb][(wy * 4 + i) * 512 + lane * 8];
      bh[i] = *(const bf16x8*)&sBH[cb][(wx * 4 + i) * 512 + lane * 8];
      bl[i] = *(const bf16x8*)&sBL[cb][(wx * 4 + i) * 512 + lane * 8];
    }
#pragma unroll
    for (int i = 0; i < 4; ++i)
#pragma unroll
      for (int j = 0; j < 4; ++j) {
        acc[i][j] = __builtin_amdgcn_mfma_f32_16x16x32_bf16(ah[i], bh[j], acc[i][j], 0, 0, 0);
        acc[i][j] = __builtin_amdgcn_mfma_f32_16x16x32_bf16(ah[i], bl[j], acc[i][j], 0, 0, 0);
        acc[i][j] = __builtin_amdgcn_mfma_f32_16x16x32_bf16(al[i], bh[j], acc[i][j], 0, 0, 0);
      }
  }
  // epilogue: C/D layout col=lane&15 (n), row=quad*4+r (m)
  if (ct == 0) {
#pragma unroll
    for (int i = 0; i < 4; ++i)
#pragma unroll
      for (int j = 0; j < 4; ++j) {
        int col = wx * 64 + j * 16 + m16;
        float bs = biascat[col];
#pragma unroll
        for (int r = 0; r < 4; ++r) {
          int row = row0 + wy * 64 + i * 16 + quad * 4 + r;
          mbuf[(size_t)row * MDIM_ + col] = acc[i][j][r] + bs;
        }
      }
  } else {
#pragma unroll
    for (int i = 0; i < 4; ++i) {
      float part[4] = {0.f, 0.f, 0.f, 0.f};
#pragma unroll
      for (int j = 0; j < 4; ++j) {
        int col = col0 + wx * 64 + j * 16 + m16;
        float bs = biascat[col];
        float wv = w2[col - MDIM_];
#pragma unroll
        for (int r = 0; r < 4; ++r) {
          float v = acc[i][j][r] + bs;
          v = v > 0.f ? v : 0.f;
          part[r] += v * wv;
        }
      }
#pragma unroll
      for (int r = 0; r < 4; ++r) {
        part[r] += __shfl_xor(part[r], 1);
        part[r] += __shfl_xor(part[r], 2);
        part[r] += __shfl_xor(part[r], 4);
        part[r] += __shfl_xor(part[r], 8);
      }
      if (m16 == 0)
#pragma unroll
        for (int r = 0; r < 4; ++r)
          atomicAdd(&logit[row0 + wy * 64 + i * 16 + quad * 4 + r], part[r]);
    }
  }
}

// ================= shared kernels (both paths) =================

// simgreedy: loads raw m rows, normalizes IN LDS (rows are window-private),
// then sim + greedy matching. One wave per window.
__global__ __launch_bounds__(256) void simgreedy(const float* __restrict__ mbuf,
    int* __restrict__ ii, int* __restrict__ jj, float* __restrict__ sv) {
  __shared__ __align__(16) float sm[4][16][132];
  int wv = threadIdx.x >> 6, lane = threadIdx.x & 63;
  int win = blockIdx.x * 4 + wv;
  int b = win >> 7, w = win & 127;
  size_t base = ((size_t)b * T_ + w * WINSZ) * MDIM_;
#pragma unroll
  for (int it = 0; it < 8; ++it) {
    int e4 = it * 64 + lane;
    int row = e4 >> 5, c4 = e4 & 31;
    float4 v = *(const float4*)(mbuf + base + (size_t)row * MDIM_ + c4 * 4);
    *(float4*)&sm[wv][row][c4 * 4] = v;
  }
  __syncthreads();
  // normalize each of the 16 rows: 4 lanes per row
  {
    int row = lane >> 2, seg = lane & 3;
    float* r = sm[wv][row] + seg * 32;
    float ss = 0.f;
#pragma unroll
    for (int k = 0; k < 32; ++k) ss += r[k] * r[k];
    ss += __shfl_xor(ss, 1);
    ss += __shfl_xor(ss, 2);
    float inv = 1.0f / sqrtf(ss);
#pragma unroll
    for (int k = 0; k < 32; ++k) r[k] *= inv;
  }
  __syncthreads();
  int a = lane >> 3, c = lane & 7;
  const float* ev = sm[wv][2 * a];
  const float* od = sm[wv][2 * c + 1];
  float s = 0.f;
#pragma unroll
  for (int k = 0; k < MDIM_; ++k) s += ev[k] * od[k];
  if (s < -10.0f) s = -__builtin_inff();
  float v = s;
  bool alive = true;
  int outb = (b * NW_ + w) * MAXP_;
  for (int p = 0; p < MAXP_; ++p) {
    float bv = alive ? v : -__builtin_inff();
    int bi = lane;
    for (int o = 32; o > 0; o >>= 1) {
      float ov = __shfl_xor(bv, o);
      int oi = __shfl_xor(bi, o);
      if (ov > bv || (ov == bv && oi < bi)) { bv = ov; bi = oi; }
    }
    int wa = bi >> 3, wc = bi & 7;
    if (lane == 0) {
      ii[outb + p] = w * WINSZ + 2 * wa;
      jj[outb + p] = w * WINSZ + 2 * wc + 1;
      sv[outb + p] = bv;
    }
    if (a == wa || c == wc) alive = false;
  }
}

// select_fused: imp (sigmoid of logit) + scores + exact stable top-k +
// alpha + rep/drop + per-batch prefix (pos). One block per batch.
__global__ __launch_bounds__(256) void select_fused(const float* __restrict__ sv,
    const int* __restrict__ ii, const int* __restrict__ jj,
    const float* __restrict__ logit, const float* __restrict__ b2,
    float* __restrict__ alpha, int* __restrict__ rep,
    int* __restrict__ drop, int* __restrict__ pos) {
  int b = blockIdx.x, tid = threadIdx.x;
  __shared__ float sc[P_];
  __shared__ int sdrop[T_];
  __shared__ int wtot[4];
  float bb = b2[0];
  for (int t = tid; t < T_; t += 256) {
    sdrop[t] = 0;
    rep[b * T_ + t] = -1;
  }
  for (int p = tid; p < P_; p += 256) {
    int i = ii[b * P_ + p], j = jj[b * P_ + p];
    float fi = 1.f / (1.f + expf(-(logit[b * T_ + i] + bb)));
    float fj = 1.f / (1.f + expf(-(logit[b * T_ + j] + bb)));
    sc[p] = sv[b * P_ + p] - 0.25f * (fi + fj);
    alpha[b * P_ + p] = 1.f / (1.f + expf(-5.f * (fi - fj)));
  }
  __syncthreads();
  for (int p = tid; p < P_; p += 256) {
    float s = sc[p];
    int cnt = 0;
    for (int q = 0; q < P_; ++q) {
      float t = sc[q];
      cnt += (t > s) || (t == s && q < p);
    }
    if (cnt < KDROP) {
      rep[b * T_ + ii[b * P_ + p]] = p;
      sdrop[jj[b * P_ + p]] = 1;
    }
  }
  __syncthreads();
  // prefix over keep mask: 8 tokens per thread
  int base = tid * 8;
  int loc[8];
  int s = 0;
#pragma unroll
  for (int k = 0; k < 8; ++k) { loc[k] = s; s += (sdrop[base + k] ? 0 : 1); }
  int lane = tid & 63, wvi = tid >> 6;
  int incl = s;
  for (int o = 1; o < 64; o <<= 1) {
    int n = __shfl_up(incl, o);
    if (lane >= o) incl += n;
  }
  if (lane == 63) wtot[wvi] = incl;
  __syncthreads();
  int carry = 0;
  for (int ww = 0; ww < wvi; ++ww) carry += wtot[ww];
  int excl = carry + incl - s;
#pragma unroll
  for (int k = 0; k < 8; ++k) {
    int t = base + k;
    drop[b * T_ + t] = sdrop[t];
    pos[b * T_ + t] = excl + loc[k];
  }
}

__global__ __launch_bounds__(256) void pack_kernel(const float* __restrict__ x,
    const int* __restrict__ drop, const int* __restrict__ pos,
    const int* __restrict__ rep, const float* __restrict__ alpha,
    const int* __restrict__ jj, float* __restrict__ out) {
  int t = blockIdx.x, b = blockIdx.y;
  if (drop[b * T_ + t]) return;
  int tid = threadIdx.x;
  const float4* xi = (const float4*)(x + ((size_t)b * T_ + t) * DIM_);
  float4 v = xi[tid];
  int p = rep[b * T_ + t];
  if (p >= 0) {
    float a = alpha[b * P_ + p];
    int j = jj[b * P_ + p];
    const float4* xj = (const float4*)(x + ((size_t)b * T_ + j) * DIM_);
    float4 vj = xj[tid];
    v.x = a * v.x + (1.f - a) * vj.x;
    v.y = a * v.y + (1.f - a) * vj.y;
    v.z = a * v.z + (1.f - a) * vj.z;
    v.w = a * v.w + (1.f - a) * vj.w;
  }
  int np = pos[b * T_ + t];
  ((float4*)(out + ((size_t)b * TKEEP + np) * DIM_))[tid] = v;
}

// ================= fallback fp32 GEMM path =================

__global__ __launch_bounds__(256) void build_wcat(const float* __restrict__ wm,
    const float* __restrict__ wi, const float* __restrict__ gm,
    const float* __restrict__ gi, float* __restrict__ Wcat) {
  int e = blockIdx.x * 256 + threadIdx.x;
  if (e >= DIM_ * NCAT) return;
  int k = e / NCAT, c = e - k * NCAT;
  float v = (c < MDIM_) ? gm[k] * wm[k * MDIM_ + c]
                        : gi[k] * wi[k * HID_ + (c - MDIM_)];
  Wcat[e] = v;
}

__global__ __launch_bounds__(256) void build_bias(const float* __restrict__ wm,
    const float* __restrict__ wi, const float* __restrict__ bm,
    const float* __restrict__ bi, const float* __restrict__ b1,
    float* __restrict__ biascat) {
  int c = blockIdx.x;
  float s = 0.f;
  for (int k = threadIdx.x; k < DIM_; k += 256)
    s += (c < MDIM_) ? bm[k] * wm[k * MDIM_ + c]
                     : bi[k] * wi[k * HID_ + (c - MDIM_)];
  __shared__ float red[256];
  red[threadIdx.x] = s; __syncthreads();
  for (int o = 128; o > 0; o >>= 1) {
    if (threadIdx.x < o) red[threadIdx.x] += red[threadIdx.x + o];
    __syncthreads();
  }
  if (threadIdx.x == 0)
    biascat[c] = red[0] + ((c >= MDIM_) ? b1[c - MDIM_] : 0.f);
}

__global__ __launch_bounds__(256) void ln_stats(const float* __restrict__ x,
    float* __restrict__ mu, float* __restrict__ rs) {
  int token = blockIdx.x * 4 + (threadIdx.x >> 6);
  int lane = threadIdx.x & 63;
  const float4* xr = (const float4*)(x + (size_t)token * DIM_);
  float4 v[4];
  float sum = 0.f;
#pragma unroll
  for (int it = 0; it < 4; ++it) {
    v[it] = xr[lane + it * 64];
    sum += v[it].x + v[it].y + v[it].z + v[it].w;
  }
  for (int o = 32; o > 0; o >>= 1) sum += __shfl_xor(sum, o);
  float m = sum * (1.f / 1024.f);
  float ss = 0.f;
#pragma unroll
  for (int it = 0; it < 4; ++it) {
    float a = v[it].x - m, b = v[it].y - m, c = v[it].z - m, d = v[it].w - m;
    ss += a * a + b * b + c * c + d * d;
  }
  for (int o = 32; o > 0; o >>= 1) ss += __shfl_xor(ss, o);
  if (lane == 0) {
    mu[token] = m;
    rs[token] = 1.0f / sqrtf(ss * (1.f / 1024.f) + 1e-5f);
  }
}

__global__ __launch_bounds__(256) void gemm640(const float* __restrict__ x,
    const float* __restrict__ mu, const float* __restrict__ rs,
    const float* __restrict__ Wcat, const float* __restrict__ biascat,
    const float* __restrict__ w2, float* __restrict__ mbuf,
    float* __restrict__ logit) {
  __shared__ __align__(16) float As[16][68];
  __shared__ __align__(16) float Bs[16][68];
  const int tid = threadIdx.x;
  const int row0 = blockIdx.x * 64, col0 = blockIdx.y * 64;
  const int tx = tid & 15, ty = tid >> 4;
  const int arow = tid >> 2, akk = (tid & 3) << 2;
  const int brow = tid >> 4, bnn = (tid & 15) << 2;
  const int t_g = row0 + arow;
  const float tmu = mu[t_g], trs = rs[t_g];
  const float* xrow = x + (size_t)t_g * DIM_ + akk;
  const float* wptr = Wcat + (size_t)brow * NCAT + col0 + bnn;
  float acc[4][4] = {};
  for (int k0 = 0; k0 < DIM_; k0 += 16) {
    float4 av = *(const float4*)(xrow + k0);
    float4 bv = *(const float4*)(wptr + (size_t)k0 * NCAT);
    As[akk + 0][arow] = (av.x - tmu) * trs;
    As[akk + 1][arow] = (av.y - tmu) * trs;
    As[akk + 2][arow] = (av.z - tmu) * trs;
    As[akk + 3][arow] = (av.w - tmu) * trs;
    *(float4*)&Bs[brow][bnn] = bv;
    __syncthreads();
#pragma unroll
    for (int k = 0; k < 16; ++k) {
      float4 a = *(const float4*)&As[k][ty << 2];
      float4 b = *(const float4*)&Bs[k][tx << 2];
      acc[0][0] += a.x * b.x; acc[0][1] += a.x * b.y; acc[0][2] += a.x * b.z; acc[0][3] += a.x * b.w;
      acc[1][0] += a.y * b.x; acc[1][1] += a.y * b.y; acc[1][2] += a.y * b.z; acc[1][3] += a.y * b.w;
      acc[2][0] += a.z * b.x; acc[2][1] += a.z * b.y; acc[2][2] += a.z * b.z; acc[2][3] += a.z * b.w;
      acc[3][0] += a.w * b.x; acc[3][1] += a.w * b.y; acc[3][2] += a.w * b.z; acc[3][3] += a.w * b.w;
    }
    __syncthreads();
  }
  float bias[4];
#pragma unroll
  for (int j = 0; j < 4; ++j) bias[j] = biascat[col0 + (tx << 2) + j];
  if (col0 < MDIM_) {
#pragma unroll
    for (int i = 0; i < 4; ++i) {
      int t = row0 + (ty << 2) + i;
      float4 o;
      o.x = acc[i][0] + bias[0]; o.y = acc[i][1] + bias[1];
      o.z = acc[i][2] + bias[2]; o.w = acc[i][3] + bias[3];
      *(float4*)(mbuf + (size_t)t * MDIM_ + col0 + (tx << 2)) = o;
    }
  } else {
    float w2v[4];
#pragma unroll
    for (int j = 0; j < 4; ++j) w2v[j] = w2[col0 - MDIM_ + (tx << 2) + j];
#pragma unroll
    for (int i = 0; i < 4; ++i) {
      float p = 0.f;
#pragma unroll
      for (int j = 0; j < 4; ++j) {
        float v = acc[i][j] + bias[j];
        v = v > 0.f ? v : 0.f;
        p += v * w2v[j];
      }
      p += __shfl_xor(p, 1); p += __shfl_xor(p, 2);
      p += __shfl_xor(p, 4); p += __shfl_xor(p, 8);
      if (tx == 0) atomicAdd(&logit[row0 + (ty << 2) + i], p);
    }
  }
}

extern "C" void kernel_launch(void* const* d_in, const int* in_sizes, int n_in,
                              void* d_out, int out_size, void* d_ws, size_t ws_size,
                              hipStream_t stream) {
  const float* x    = (const float*)d_in[0];
  const float* gm   = (const float*)d_in[1];
  const float* bm   = (const float*)d_in[2];
  const float* wm   = (const float*)d_in[3];
  const float* gi   = (const float*)d_in[4];
  const float* bi   = (const float*)d_in[5];
  const float* wi   = (const float*)d_in[6];
  const float* b1   = (const float*)d_in[7];
  const float* w2   = (const float*)d_in[8];
  const float* b2   = (const float*)d_in[9];
  float* ws = (float*)d_ws;
  float* out = (float*)d_out;

  if (ws_size >= F_TOTAL * sizeof(float)) {
    // -------- fast path: bf16x2-split MFMA GEMM (double-buffered) --------
    u16* Ah = (u16*)(ws + F_AH);
    u16* Al = (u16*)(ws + F_AL);
    u16* Bh = (u16*)(ws + F_BH);
    u16* Bl = (u16*)(ws + F_BL);
    float* bias  = ws + F_BIAS;
    float* mbuf  = ws + F_MBUF;
    float* logit = ws + F_LOGIT;
    int* iidx    = (int*)(ws + F_IIDX);
    int* jidx    = (int*)(ws + F_JIDX);
    float* sv    = ws + F_SV;
    float* alpha = ws + F_ALPHA;
    int* rep     = (int*)(ws + F_REP);
    int* drop    = (int*)(ws + F_DROP);
    int* pos     = (int*)(ws + F_POS);

    hipMemsetAsync(logit, 0, NTOK * sizeof(float), stream);
    prep_w<<<(NCAT * DIM_) / 256 + NCAT, 256, 0, stream>>>(wm, wi, gm, gi, bm, bi, b1, Bh, Bl, bias);
    prep_a<<<NTOK / 4, 256, 0, stream>>>(x, Ah, Al);
    gemm_mfma<<<(NTOK / 128) * (NCAT / 128), 256, 0, stream>>>(Ah, Al, Bh, Bl, bias, w2, mbuf, logit);
    simgreedy<<<(B_ * NW_) / 4, 256, 0, stream>>>(mbuf, iidx, jidx, sv);
    select_fused<<<B_, 256, 0, stream>>>(sv, iidx, jidx, logit, b2, alpha, rep, drop, pos);
    dim3 pgrid(T_, B_);
    pack_kernel<<<pgrid, 256, 0, stream>>>(x, drop, pos, rep, alpha, jidx, out);
  } else {
    // -------- fallback: fp32 vector-ALU path --------
    float* Wcat = ws + OFF_WCAT;
    float* bias = ws + OFF_BIAS;
    float* mu   = ws + OFF_MU;
    float* rs   = ws + OFF_RS;
    float* mbuf = ws + OFF_MBUF;
    float* logit = ws + OFF_LOGIT;
    int* iidx   = (int*)(ws + OFF_IIDX);
    int* jidx   = (int*)(ws + OFF_JIDX);
    float* sv   = ws + OFF_SV;
    float* alpha = ws + OFF_ALPHA;
    int* rep    = (int*)(ws + OFF_REP);
    int* drop   = (int*)(ws + OFF_DROP);
    int* pos    = (int*)(ws + OFF_POS);

    hipMemsetAsync(logit, 0, NTOK * sizeof(float), stream);
    build_wcat<<<(DIM_ * NCAT + 255) / 256, 256, 0, stream>>>(wm, wi, gm, gi, Wcat);
    build_bias<<<NCAT, 256, 0, stream>>>(wm, wi, bm, bi, b1, bias);
    ln_stats<<<NTOK / 4, 256, 0, stream>>>(x, mu, rs);
    dim3 ggrid(NTOK / 64, NCAT / 64);
    gemm640<<<ggrid, 256, 0, stream>>>(x, mu, rs, Wcat, bias, w2, mbuf, logit);
    simgreedy<<<(B_ * NW_) / 4, 256, 0, stream>>>(mbuf, iidx, jidx, sv);
    select_fused<<<B_, 256, 0, stream>>>(sv, iidx, jidx, logit, b2, alpha, rep, drop, pos);
    dim3 pgrid(T_, B_);
    pack_kernel<<<pgrid, 256, 0, stream>>>(x, drop, pos, rep, alpha, jidx, out);
  }
}